// Round 5
// baseline (251.791 us; speedup 1.0000x reference)
//
#include <hip/hip_runtime.h>
#include <hip/hip_bf16.h>

#define BN 8192
#define DIM 512
#define NB  64            // BN / 128 block-rows
#define EPSF 1e-8f

using v8i   = __attribute__((ext_vector_type(8))) int;
using v4i   = __attribute__((ext_vector_type(4))) int;
using f32x4 = __attribute__((ext_vector_type(4))) float;

// Async global->LDS, 16 B per lane, dest = uniform base + lane*16.
__device__ inline void async_copy16(const void* g, void* l) {
    __builtin_amdgcn_global_load_lds(
        (const __attribute__((address_space(1))) void*)g,
        (__attribute__((address_space(3))) void*)l,
        16, 0, 0);
}

// One wave per row: L2-normalize, scale by 4, convert to fp8 e4m3.
// (x4 pre-scale keeps values in e4m3 normal range; S = acc/16 in epilogue.)
__global__ __launch_bounds__(256) void normalize_kernel(
        const float* __restrict__ emb, unsigned char* __restrict__ E) {
    int wave = threadIdx.x >> 6;
    int lane = threadIdx.x & 63;
    int row  = blockIdx.x * 4 + wave;
    const float4* src = (const float4*)(emb + (size_t)row * DIM);
    float4 a = src[lane];        // elems 4*lane .. +4       (coalesced)
    float4 b = src[lane + 64];   // elems 256+4*lane .. +4   (coalesced)
    float ss = a.x*a.x + a.y*a.y + a.z*a.z + a.w*a.w
             + b.x*b.x + b.y*b.y + b.z*b.z + b.w*b.w;
    #pragma unroll
    for (int m = 1; m < 64; m <<= 1) ss += __shfl_xor(ss, m, 64);
    float s4 = 4.0f / fmaxf(sqrtf(ss), 1e-12f);
    int pa = __builtin_amdgcn_cvt_pk_fp8_f32(a.x*s4, a.y*s4, 0, false);
    pa     = __builtin_amdgcn_cvt_pk_fp8_f32(a.z*s4, a.w*s4, pa, true);
    int pb = __builtin_amdgcn_cvt_pk_fp8_f32(b.x*s4, b.y*s4, 0, false);
    pb     = __builtin_amdgcn_cvt_pk_fp8_f32(b.z*s4, b.w*s4, pb, true);
    unsigned char* rowp = E + (size_t)row * DIM;
    ((unsigned*)rowp)[lane]         = (unsigned)pa;   // bytes 4*lane
    ((unsigned*)(rowp + 256))[lane] = (unsigned)pb;   // bytes 256+4*lane
}

// Upper-triangle 128x128 tiles, 1D grid (2080), triangular decode.
// fp8 e4m3, MX-scaled MFMA 16x16x128 (scale=1.0 -> 0x7F), BK=128,
// SINGLE-buffered m97-style K-loop (stage -> barrier -> compute): the
// vmcnt drain sits at the barrier where it belongs; latency is hidden by
// ~3 co-resident blocks (m114 wave-level overlap), not in-wave prefetch.
// XOR chunk swizzle (16B chunks, chunk^row within 8-row groups) keeps the
// ds_read_b128 fragment loads <=2-way bank-conflicted (free).
__global__ __launch_bounds__(256, 3) void gemm_epi_kernel(
        const unsigned char* __restrict__ E, const int* __restrict__ labels,
        float* __restrict__ P, float* __restrict__ N) {
    constexpr int BI = 128, BK = 128, KITERS = DIM / BK;   // 4

    int t  = blockIdx.x;
    int bi = (int)(64.5f - sqrtf(64.5f * 64.5f - 2.0f * (float)t));
    while (64 * (bi + 1) - ((bi + 1) * bi) / 2 <= t) ++bi;
    while (64 * bi - (bi * (bi - 1)) / 2 > t) --bi;
    int bj = bi + (t - (64 * bi - (bi * (bi - 1)) / 2));
    const bool diag = (bi == bj);

    __shared__ unsigned char As[BI][BK];   // 16 KB
    __shared__ unsigned char Bs[BI][BK];   // 16 KB
    __shared__ int labI[BI];
    __shared__ int labJ[BI];
    __shared__ float rowP[BI][2], rowN[BI][2];
    __shared__ float colP[BI][2], colN[BI][2];

    const int tid  = threadIdx.x;
    const int i0   = bi * BI;
    const int j0   = bj * BI;
    const int wave = tid >> 6;
    const int lane = tid & 63;
    const int quad = lane >> 4;    // 0..3
    const int lrow = lane & 15;    // 0..15
    const int i_w  = (wave >> 1) * 64;
    const int j_w  = (wave & 1) * 64;

    if (tid < 128)       labI[tid]       = labels[i0 + tid];
    else                 labJ[tid - 128] = labels[j0 + tid - 128];

    f32x4 acc[4][4];
    #pragma unroll
    for (int a = 0; a < 4; ++a)
        #pragma unroll
        for (int b = 0; b < 4; ++b)
            acc[a][b] = (f32x4){0.f, 0.f, 0.f, 0.f};

    // Staging: wave covers rows [wave*32, wave*32+32) as 4 instrs of 8 rows.
    // Lane l: local row lr=l>>3, LDS chunk ck=l&7; fetch global chunk ck^lr.
    const int lr = lane >> 3;
    const int gc = (lane & 7) ^ lr;

    for (int k = 0; k < KITERS; ++k) {
        __syncthreads();                  // prev iter's ds_reads done
        #pragma unroll
        for (int h = 0; h < 4; ++h) {
            int r0 = wave * 32 + h * 8;
            async_copy16(E + (size_t)(i0 + r0 + lr) * DIM + k * BK + gc * 16,
                         &As[r0][0]);
            async_copy16(E + (size_t)(j0 + r0 + lr) * DIM + k * BK + gc * 16,
                         &Bs[r0][0]);
        }
        __syncthreads();                  // vmcnt drain happens HERE

        // Fragment loads: lane (row lrow, k-quad) needs global chunks
        // quad*2, quad*2+1. LDS chunk = global chunk ^ (R&7).
        v8i af[4];
        #pragma unroll
        for (int tt = 0; tt < 4; ++tt) {
            int R  = i_w + tt * 16 + lrow;
            const v4i* rp = (const v4i*)&As[R][0];
            int sw = R & 7;
            v4i lo = rp[(quad * 2) ^ sw];
            v4i hi = rp[(quad * 2 + 1) ^ sw];
            af[tt] = (v8i){lo[0], lo[1], lo[2], lo[3],
                           hi[0], hi[1], hi[2], hi[3]};
        }
        #pragma unroll
        for (int tj = 0; tj < 4; ++tj) {
            int R  = j_w + tj * 16 + lrow;
            const v4i* rp = (const v4i*)&Bs[R][0];
            int sw = R & 7;
            v4i lo = rp[(quad * 2) ^ sw];
            v4i hi = rp[(quad * 2 + 1) ^ sw];
            v8i bf = (v8i){lo[0], lo[1], lo[2], lo[3],
                           hi[0], hi[1], hi[2], hi[3]};
            #pragma unroll
            for (int ti = 0; ti < 4; ++ti)
                acc[ti][tj] = __builtin_amdgcn_mfma_scale_f32_16x16x128_f8f6f4(
                                  af[ti], bf, acc[ti][tj],
                                  0, 0,                 // cbsz/blgp: fp8 e4m3
                                  0, 0x7F7F7F7F,        // A scale = 1.0
                                  0, 0x7F7F7F7F);       // B scale = 1.0
        }
    }

    // Epilogue. C/D layout: col = lane&15, row = quad*4 + reg. acc = 16*S.
    float psC[4] = {0.f, 0.f, 0.f, 0.f};
    float nsC[4] = {0.f, 0.f, 0.f, 0.f};
    #pragma unroll
    for (int ti = 0; ti < 4; ++ti) {
        #pragma unroll
        for (int reg = 0; reg < 4; ++reg) {
            int irow = i_w + ti * 16 + quad * 4 + reg;
            int li   = labI[irow];
            int gi   = i0 + irow;
            float ps = 0.f, ns = 0.f;
            #pragma unroll
            for (int tj = 0; tj < 4; ++tj) {
                int jcol = j_w + tj * 16 + lrow;
                int lj   = labJ[jcol];
                int gj   = j0 + jcol;
                float w  = __expf(fmaf(acc[ti][tj][reg], 0.0625f, -1.0f));
                bool same = (li == lj);
                float wp = (same && (gi != gj)) ? w : 0.f;
                float wn = same ? 0.f : w;
                ps += wp;  ns += wn;
                psC[tj] += wp;  nsC[tj] += wn;
            }
            #pragma unroll
            for (int m = 1; m < 16; m <<= 1) {
                ps += __shfl_xor(ps, m, 64);
                ns += __shfl_xor(ns, m, 64);
            }
            if (lrow == 0) {
                rowP[irow][wave & 1] = ps;
                rowN[irow][wave & 1] = ns;
            }
        }
    }
    #pragma unroll
    for (int tj = 0; tj < 4; ++tj) {
        float ps = psC[tj], ns = nsC[tj];
        ps += __shfl_xor(ps, 16, 64);  ns += __shfl_xor(ns, 16, 64);
        ps += __shfl_xor(ps, 32, 64);  ns += __shfl_xor(ns, 32, 64);
        if (lane < 16) {
            int jc = j_w + tj * 16 + lrow;
            colP[jc][wave >> 1] = ps;
            colN[jc][wave >> 1] = ns;
        }
    }
    __syncthreads();
    int r = tid & 127;
    if (tid < 128) {
        P[(size_t)bj * BN + i0 + r] = rowP[r][0] + rowP[r][1];
        N[(size_t)bj * BN + i0 + r] = rowN[r][0] + rowN[r][1];
    } else if (!diag) {
        P[(size_t)bi * BN + j0 + r] = colP[r][0] + colP[r][1];
        N[(size_t)bi * BN + j0 + r] = colN[r][0] + colN[r][1];
    }
}

// Fused tail: 32 blocks x 256. Per-block LDS histogram (redundant, no global
// atomics / no cnt memset), per-row partial reduce + loss, one atomicAdd of
// the pre-scaled block sum into out[0] (zeroed by memsetAsync).
__global__ __launch_bounds__(256) void reduce_finalize_kernel(
        const int* __restrict__ labels, const float* __restrict__ P,
        const float* __restrict__ N, float* __restrict__ out) {
    __shared__ int cnt[128];
    __shared__ float wsum[4];
    int tid = threadIdx.x;
    if (tid < 128) cnt[tid] = 0;
    __syncthreads();
    for (int i = tid; i < BN; i += 256) atomicAdd(&cnt[labels[i]], 1);
    __syncthreads();

    int i = blockIdx.x * 256 + tid;
    float p = 0.f, n = 0.f;
    #pragma unroll 8
    for (int c = 0; c < NB; ++c) {
        p += P[(size_t)c * BN + i];
        n += N[(size_t)c * BN + i];
    }
    int   c  = cnt[labels[i]];
    float pc = (float)(c - 1);
    float nc = (float)(BN - c);
    float pm = p / fmaxf(pc, 1.0f);
    float nm = n / fmaxf(nc, 1.0f);
    float v  = ((c - 1 > 0) && (BN - c > 0))
                   ? -logf(pm / (pm + nm + EPSF)) : 0.0f;
    v *= (1.0f / (float)BN);

    #pragma unroll
    for (int m = 1; m < 64; m <<= 1) v += __shfl_xor(v, m, 64);
    if ((tid & 63) == 0) wsum[tid >> 6] = v;
    __syncthreads();
    if (tid == 0)
        atomicAdd(out, wsum[0] + wsum[1] + wsum[2] + wsum[3]);
}

extern "C" void kernel_launch(void* const* d_in, const int* in_sizes, int n_in,
                              void* d_out, int out_size, void* d_ws, size_t ws_size,
                              hipStream_t stream) {
    const float* emb   = (const float*)d_in[0];
    const int* labels  = (const int*)d_in[1];
    float* out         = (float*)d_out;

    // ws layout: E (8 MB reserved; fp8 uses 4) | P (2 MB) | N (2 MB)
    unsigned char* E   = (unsigned char*)d_ws;
    float* P           = (float*)((char*)d_ws + (size_t)BN * DIM * 2);
    float* N           = P + (size_t)NB * BN;

    hipMemsetAsync(out, 0, sizeof(float), stream);
    normalize_kernel<<<BN / 4, 256, 0, stream>>>(emb, E);
    gemm_epi_kernel<<<NB * (NB + 1) / 2, 256, 0, stream>>>(E, labels, P, N);
    reduce_finalize_kernel<<<BN / 256, 256, 0, stream>>>(labels, P, N, out);
}

// Round 6
// 153.882 us; speedup vs baseline: 1.6363x; 1.6363x over previous
//
#include <hip/hip_runtime.h>
#include <hip/hip_bf16.h>

#define BN 8192
#define DIM 512
#define NB  64            // BN / 128 block-rows
#define EPSF 1e-8f

using v8i   = __attribute__((ext_vector_type(8))) int;
using v4i   = __attribute__((ext_vector_type(4))) int;
using f32x4 = __attribute__((ext_vector_type(4))) float;

// Async global->LDS, 16 B per lane, dest = uniform base + lane*16.
__device__ inline void async_copy16(const void* g, void* l) {
    __builtin_amdgcn_global_load_lds(
        (const __attribute__((address_space(1))) void*)g,
        (__attribute__((address_space(3))) void*)l,
        16, 0, 0);
}

// One wave per row: L2-normalize, scale by 4, convert to fp8 e4m3.
// (x4 pre-scale keeps values in e4m3 normal range; S = acc/16 in epilogue.)
// Also zeroes out[0] (replaces a separate memset dispatch; stream order
// guarantees it lands before reduce_finalize_kernel's atomicAdd).
__global__ __launch_bounds__(256) void normalize_kernel(
        const float* __restrict__ emb, unsigned char* __restrict__ E,
        float* __restrict__ out) {
    if (blockIdx.x == 0 && threadIdx.x == 0) out[0] = 0.f;
    int wave = threadIdx.x >> 6;
    int lane = threadIdx.x & 63;
    int row  = blockIdx.x * 4 + wave;
    const float4* src = (const float4*)(emb + (size_t)row * DIM);
    float4 a = src[lane];        // elems 4*lane .. +4       (coalesced)
    float4 b = src[lane + 64];   // elems 256+4*lane .. +4   (coalesced)
    float ss = a.x*a.x + a.y*a.y + a.z*a.z + a.w*a.w
             + b.x*b.x + b.y*b.y + b.z*b.z + b.w*b.w;
    #pragma unroll
    for (int m = 1; m < 64; m <<= 1) ss += __shfl_xor(ss, m, 64);
    float s4 = 4.0f / fmaxf(sqrtf(ss), 1e-12f);
    int pa = __builtin_amdgcn_cvt_pk_fp8_f32(a.x*s4, a.y*s4, 0, false);
    pa     = __builtin_amdgcn_cvt_pk_fp8_f32(a.z*s4, a.w*s4, pa, true);
    int pb = __builtin_amdgcn_cvt_pk_fp8_f32(b.x*s4, b.y*s4, 0, false);
    pb     = __builtin_amdgcn_cvt_pk_fp8_f32(b.z*s4, b.w*s4, pb, true);
    unsigned char* rowp = E + (size_t)row * DIM;
    ((unsigned*)rowp)[lane]         = (unsigned)pa;   // bytes 4*lane
    ((unsigned*)(rowp + 256))[lane] = (unsigned)pb;   // bytes 256+4*lane
}

// Upper-triangle 128x128 tiles, 1D grid (2080), triangular decode.
// fp8 e4m3, MX-scaled MFMA 16x16x128 (scale=1.0 -> 0x7F), BK=128,
// SINGLE-buffered K-loop (stage -> barrier -> compute), 37 KB LDS so up to
// 3-4 blocks/CU co-reside; cross-block overlap (m114) hides the barrier
// drain. NO launch-bounds min-waves: R5 proved forcing 3 waves/EU spills
// (VGPR 152->84, +600 MB scratch traffic, 2x regression).
// XOR chunk swizzle (16B chunks, chunk^row within 8-row groups) keeps the
// ds_read_b128 fragment loads <=2-way bank-conflicted (free per m136).
__global__ __launch_bounds__(256) void gemm_epi_kernel(
        const unsigned char* __restrict__ E, const int* __restrict__ labels,
        float* __restrict__ P, float* __restrict__ N) {
    constexpr int BI = 128, BK = 128, KITERS = DIM / BK;   // 4

    int t  = blockIdx.x;
    int bi = (int)(64.5f - sqrtf(64.5f * 64.5f - 2.0f * (float)t));
    while (64 * (bi + 1) - ((bi + 1) * bi) / 2 <= t) ++bi;
    while (64 * bi - (bi * (bi - 1)) / 2 > t) --bi;
    int bj = bi + (t - (64 * bi - (bi * (bi - 1)) / 2));
    const bool diag = (bi == bj);

    __shared__ unsigned char As[BI][BK];   // 16 KB
    __shared__ unsigned char Bs[BI][BK];   // 16 KB
    __shared__ int labI[BI];
    __shared__ int labJ[BI];
    __shared__ float rowP[BI][2], rowN[BI][2];
    __shared__ float colP[BI][2], colN[BI][2];

    const int tid  = threadIdx.x;
    const int i0   = bi * BI;
    const int j0   = bj * BI;
    const int wave = tid >> 6;
    const int lane = tid & 63;
    const int quad = lane >> 4;    // 0..3
    const int lrow = lane & 15;    // 0..15
    const int i_w  = (wave >> 1) * 64;
    const int j_w  = (wave & 1) * 64;

    if (tid < 128)       labI[tid]       = labels[i0 + tid];
    else                 labJ[tid - 128] = labels[j0 + tid - 128];

    f32x4 acc[4][4];
    #pragma unroll
    for (int a = 0; a < 4; ++a)
        #pragma unroll
        for (int b = 0; b < 4; ++b)
            acc[a][b] = (f32x4){0.f, 0.f, 0.f, 0.f};

    // Staging: wave covers rows [wave*32, wave*32+32) as 4 instrs of 8 rows.
    // Lane l: local row lr=l>>3, LDS chunk ck=l&7; fetch global chunk ck^lr.
    const int lr = lane >> 3;
    const int gc = (lane & 7) ^ lr;

    for (int k = 0; k < KITERS; ++k) {
        __syncthreads();                  // prev iter's ds_reads done
        #pragma unroll
        for (int h = 0; h < 4; ++h) {
            int r0 = wave * 32 + h * 8;
            async_copy16(E + (size_t)(i0 + r0 + lr) * DIM + k * BK + gc * 16,
                         &As[r0][0]);
            async_copy16(E + (size_t)(j0 + r0 + lr) * DIM + k * BK + gc * 16,
                         &Bs[r0][0]);
        }
        __syncthreads();                  // vmcnt drain happens HERE

        // Fragment loads: lane (row lrow, k-quad) needs global chunks
        // quad*2, quad*2+1. LDS chunk = global chunk ^ (R&7).
        v8i af[4];
        #pragma unroll
        for (int tt = 0; tt < 4; ++tt) {
            int R  = i_w + tt * 16 + lrow;
            const v4i* rp = (const v4i*)&As[R][0];
            int sw = R & 7;
            v4i lo = rp[(quad * 2) ^ sw];
            v4i hi = rp[(quad * 2 + 1) ^ sw];
            af[tt] = (v8i){lo[0], lo[1], lo[2], lo[3],
                           hi[0], hi[1], hi[2], hi[3]};
        }
        #pragma unroll
        for (int tj = 0; tj < 4; ++tj) {
            int R  = j_w + tj * 16 + lrow;
            const v4i* rp = (const v4i*)&Bs[R][0];
            int sw = R & 7;
            v4i lo = rp[(quad * 2) ^ sw];
            v4i hi = rp[(quad * 2 + 1) ^ sw];
            v8i bf = (v8i){lo[0], lo[1], lo[2], lo[3],
                           hi[0], hi[1], hi[2], hi[3]};
            #pragma unroll
            for (int ti = 0; ti < 4; ++ti)
                acc[ti][tj] = __builtin_amdgcn_mfma_scale_f32_16x16x128_f8f6f4(
                                  af[ti], bf, acc[ti][tj],
                                  0, 0,                 // cbsz/blgp: fp8 e4m3
                                  0, 0x7F7F7F7F,        // A scale = 1.0
                                  0, 0x7F7F7F7F);       // B scale = 1.0
        }
    }

    // Epilogue. C/D layout: col = lane&15, row = quad*4 + reg. acc = 16*S.
    float psC[4] = {0.f, 0.f, 0.f, 0.f};
    float nsC[4] = {0.f, 0.f, 0.f, 0.f};
    #pragma unroll
    for (int ti = 0; ti < 4; ++ti) {
        #pragma unroll
        for (int reg = 0; reg < 4; ++reg) {
            int irow = i_w + ti * 16 + quad * 4 + reg;
            int li   = labI[irow];
            int gi   = i0 + irow;
            float ps = 0.f, ns = 0.f;
            #pragma unroll
            for (int tj = 0; tj < 4; ++tj) {
                int jcol = j_w + tj * 16 + lrow;
                int lj   = labJ[jcol];
                int gj   = j0 + jcol;
                float w  = __expf(fmaf(acc[ti][tj][reg], 0.0625f, -1.0f));
                bool same = (li == lj);
                float wp = (same && (gi != gj)) ? w : 0.f;
                float wn = same ? 0.f : w;
                ps += wp;  ns += wn;
                psC[tj] += wp;  nsC[tj] += wn;
            }
            #pragma unroll
            for (int m = 1; m < 16; m <<= 1) {
                ps += __shfl_xor(ps, m, 64);
                ns += __shfl_xor(ns, m, 64);
            }
            if (lrow == 0) {
                rowP[irow][wave & 1] = ps;
                rowN[irow][wave & 1] = ns;
            }
        }
    }
    #pragma unroll
    for (int tj = 0; tj < 4; ++tj) {
        float ps = psC[tj], ns = nsC[tj];
        ps += __shfl_xor(ps, 16, 64);  ns += __shfl_xor(ns, 16, 64);
        ps += __shfl_xor(ps, 32, 64);  ns += __shfl_xor(ns, 32, 64);
        if (lane < 16) {
            int jc = j_w + tj * 16 + lrow;
            colP[jc][wave >> 1] = ps;
            colN[jc][wave >> 1] = ns;
        }
    }
    __syncthreads();
    int r = tid & 127;
    if (tid < 128) {
        P[(size_t)bj * BN + i0 + r] = rowP[r][0] + rowP[r][1];
        N[(size_t)bj * BN + i0 + r] = rowN[r][0] + rowN[r][1];
    } else if (!diag) {
        P[(size_t)bi * BN + j0 + r] = colP[r][0] + colP[r][1];
        N[(size_t)bi * BN + j0 + r] = colN[r][0] + colN[r][1];
    }
}

// Fused tail: 32 blocks x 256. Per-block LDS histogram (redundant, no global
// atomics / no cnt memset), per-row partial reduce + loss, one atomicAdd of
// the pre-scaled block sum into out[0] (zeroed by normalize_kernel).
__global__ __launch_bounds__(256) void reduce_finalize_kernel(
        const int* __restrict__ labels, const float* __restrict__ P,
        const float* __restrict__ N, float* __restrict__ out) {
    __shared__ int cnt[128];
    __shared__ float wsum[4];
    int tid = threadIdx.x;
    if (tid < 128) cnt[tid] = 0;
    __syncthreads();
    for (int i = tid; i < BN; i += 256) atomicAdd(&cnt[labels[i]], 1);
    __syncthreads();

    int i = blockIdx.x * 256 + tid;
    float p = 0.f, n = 0.f;
    #pragma unroll 8
    for (int c = 0; c < NB; ++c) {
        p += P[(size_t)c * BN + i];
        n += N[(size_t)c * BN + i];
    }
    int   c  = cnt[labels[i]];
    float pc = (float)(c - 1);
    float nc = (float)(BN - c);
    float pm = p / fmaxf(pc, 1.0f);
    float nm = n / fmaxf(nc, 1.0f);
    float v  = ((c - 1 > 0) && (BN - c > 0))
                   ? -logf(pm / (pm + nm + EPSF)) : 0.0f;
    v *= (1.0f / (float)BN);

    #pragma unroll
    for (int m = 1; m < 64; m <<= 1) v += __shfl_xor(v, m, 64);
    if ((tid & 63) == 0) wsum[tid >> 6] = v;
    __syncthreads();
    if (tid == 0)
        atomicAdd(out, wsum[0] + wsum[1] + wsum[2] + wsum[3]);
}

extern "C" void kernel_launch(void* const* d_in, const int* in_sizes, int n_in,
                              void* d_out, int out_size, void* d_ws, size_t ws_size,
                              hipStream_t stream) {
    const float* emb   = (const float*)d_in[0];
    const int* labels  = (const int*)d_in[1];
    float* out         = (float*)d_out;

    // ws layout: E (8 MB reserved; fp8 uses 4) | P (2 MB) | N (2 MB)
    unsigned char* E   = (unsigned char*)d_ws;
    float* P           = (float*)((char*)d_ws + (size_t)BN * DIM * 2);
    float* N           = P + (size_t)NB * BN;

    normalize_kernel<<<BN / 4, 256, 0, stream>>>(emb, E, out);
    gemm_epi_kernel<<<NB * (NB + 1) / 2, 256, 0, stream>>>(E, labels, P, N);
    reduce_finalize_kernel<<<BN / 256, 256, 0, stream>>>(labels, P, N, out);
}

// Round 7
// 129.328 us; speedup vs baseline: 1.9469x; 1.1899x over previous
//
#include <hip/hip_runtime.h>
#include <hip/hip_bf16.h>

#define BN 8192
#define DIM 512
#define NB  64            // BN / 128 block-rows
#define EPSF 1e-8f

using v8i   = __attribute__((ext_vector_type(8))) int;
using v4i   = __attribute__((ext_vector_type(4))) int;
using f32x4 = __attribute__((ext_vector_type(4))) float;

// Async global->LDS, 16 B per lane, dest = uniform base + lane*16.
__device__ inline void async_copy16(const void* g, void* l) {
    __builtin_amdgcn_global_load_lds(
        (const __attribute__((address_space(1))) void*)g,
        (__attribute__((address_space(3))) void*)l,
        16, 0, 0);
}

// One wave per row: L2-normalize, scale by 4, convert to fp8 e4m3.
// (x4 pre-scale keeps values in e4m3 normal range; S = acc/16 in epilogue.)
// Also zeroes out[0] (replaces a memset dispatch).
__global__ __launch_bounds__(256) void normalize_kernel(
        const float* __restrict__ emb, unsigned char* __restrict__ E,
        float* __restrict__ out) {
    if (blockIdx.x == 0 && threadIdx.x == 0) out[0] = 0.f;
    int wave = threadIdx.x >> 6;
    int lane = threadIdx.x & 63;
    int row  = blockIdx.x * 4 + wave;
    const float4* src = (const float4*)(emb + (size_t)row * DIM);
    float4 a = src[lane];
    float4 b = src[lane + 64];
    float ss = a.x*a.x + a.y*a.y + a.z*a.z + a.w*a.w
             + b.x*b.x + b.y*b.y + b.z*b.z + b.w*b.w;
    #pragma unroll
    for (int m = 1; m < 64; m <<= 1) ss += __shfl_xor(ss, m, 64);
    float s4 = 4.0f / fmaxf(sqrtf(ss), 1e-12f);
    int pa = __builtin_amdgcn_cvt_pk_fp8_f32(a.x*s4, a.y*s4, 0, false);
    pa     = __builtin_amdgcn_cvt_pk_fp8_f32(a.z*s4, a.w*s4, pa, true);
    int pb = __builtin_amdgcn_cvt_pk_fp8_f32(b.x*s4, b.y*s4, 0, false);
    pb     = __builtin_amdgcn_cvt_pk_fp8_f32(b.z*s4, b.w*s4, pb, true);
    unsigned char* rowp = E + (size_t)row * DIM;
    ((unsigned*)rowp)[lane]         = (unsigned)pa;
    ((unsigned*)(rowp + 256))[lane] = (unsigned)pb;
}

// Upper-triangle 128x128 tiles, 1D grid (2080), triangular decode.
// NEW STRUCTURE (R7): full A-slab (128x512 fp8 = 64 KB) resident in LDS,
// staged ONCE (one barrier). B fragments load directly global->VGPR from the
// L2-resident E (4 MB) -- the K-loop has ZERO barriers, so the compiler can
// pipeline B loads across all 4 k-iters with fine-grained vmcnt (AITER-style).
// A-slab XOR swizzle: LDS chunk p of row r holds global chunk p ^ (r&7) ->
// fragment ds_read_b128 spreads over all 32 banks (bank-optimal).
// Epilogue: LDS-buffer reduction (reusing the As memory) instead of 144
// cross-lane shuffles per lane -- DS-pipe cost cut ~5x.
__global__ __launch_bounds__(256) void gemm_epi_kernel(
        const unsigned char* __restrict__ E, const int* __restrict__ labels,
        float* __restrict__ P, float* __restrict__ N) {
    int t  = blockIdx.x;
    int bi = (int)(64.5f - sqrtf(64.5f * 64.5f - 2.0f * (float)t));
    while (64 * (bi + 1) - ((bi + 1) * bi) / 2 <= t) ++bi;
    while (64 * bi - (bi * (bi - 1)) / 2 > t) --bi;
    int bj = bi + (t - (64 * bi - (bi * (bi - 1)) / 2));
    const bool diag = (bi == bj);

    __shared__ __attribute__((aligned(16))) unsigned char As[128 * DIM]; // 64 KB
    __shared__ int labI[128];
    __shared__ int labJ[128];

    const int tid  = threadIdx.x;
    const int i0   = bi * 128;
    const int j0   = bj * 128;
    const int wave = tid >> 6;
    const int lane = tid & 63;
    const int quad = lane >> 4;    // 0..3
    const int lrow = lane & 15;    // 0..15
    const int i_w  = (wave >> 1) * 64;
    const int j_w  = (wave & 1) * 64;

    if (tid < 128)       labI[tid]       = labels[i0 + tid];
    else                 labJ[tid - 128] = labels[j0 + tid - 128];

    f32x4 acc[4][4];
    #pragma unroll
    for (int a = 0; a < 4; ++a)
        #pragma unroll
        for (int b = 0; b < 4; ++b)
            acc[a][b] = (f32x4){0.f, 0.f, 0.f, 0.f};

    // Stage full A slab: wave w covers rows [w*32, w*32+32), 16 instrs x 1 KB
    // (2 rows each). Lane l: row = base + (l>>5), LDS chunk p = l&31 holds
    // global chunk p ^ (row&7).
    {
        const int ck  = lane & 31;
        const int lr2 = lane >> 5;
        #pragma unroll
        for (int h = 0; h < 16; ++h) {
            int base = wave * 32 + h * 2;
            int rowg = base + lr2;
            int g    = ck ^ (rowg & 7);
            async_copy16(E + (size_t)(i0 + rowg) * DIM + g * 16,
                         As + (size_t)base * DIM);
        }
    }
    __syncthreads();      // vmcnt drain: As + labels ready. ONLY k-loop barrier.

    #pragma unroll
    for (int k = 0; k < 4; ++k) {
        v8i af[4], bf[4];
        #pragma unroll
        for (int ti = 0; ti < 4; ++ti) {
            int r  = i_w + ti * 16 + lrow;
            const v4i* rp = (const v4i*)(As + (size_t)r * DIM);
            int sw = r & 7;
            v4i lo = rp[(k * 8 + quad * 2) ^ sw];
            v4i hi = rp[(k * 8 + quad * 2 + 1) ^ sw];
            af[ti] = (v8i){lo[0], lo[1], lo[2], lo[3],
                           hi[0], hi[1], hi[2], hi[3]};
        }
        #pragma unroll
        for (int tj = 0; tj < 4; ++tj) {
            const v4i* gp = (const v4i*)(E +
                (size_t)(j0 + j_w + tj * 16 + lrow) * DIM + k * 128 + quad * 32);
            v4i lo = gp[0];
            v4i hi = gp[1];
            bf[tj] = (v8i){lo[0], lo[1], lo[2], lo[3],
                           hi[0], hi[1], hi[2], hi[3]};
        }
        #pragma unroll
        for (int ti = 0; ti < 4; ++ti)
            #pragma unroll
            for (int tj = 0; tj < 4; ++tj)
                acc[ti][tj] = __builtin_amdgcn_mfma_scale_f32_16x16x128_f8f6f4(
                                  af[ti], bf[tj], acc[ti][tj],
                                  0, 0,                 // fp8 e4m3 / e4m3
                                  0, 0x7F7F7F7F,        // A scale = 1.0
                                  0, 0x7F7F7F7F);       // B scale = 1.0
    }
    __syncthreads();      // all ds_reads of As done -> reuse as reduction bufs

    // Reuse As memory: rowBuf [256][18] float2 (36.9 KB), colBuf [256][6]
    // float2 (12.3 KB). Variant index: rowBuf v = j_w>>6, colBuf v = i_w>>6
    // (the two waves sharing an i-range have different j_w and vice versa).
    float2* rowBuf = (float2*)As;
    float2* colBuf = (float2*)(As + 256 * 18 * 8);
    const int vR = (j_w >> 6);
    const int vC = (i_w >> 6);

    float psC[4] = {0.f, 0.f, 0.f, 0.f};
    float nsC[4] = {0.f, 0.f, 0.f, 0.f};
    #pragma unroll
    for (int ti = 0; ti < 4; ++ti) {
        #pragma unroll
        for (int reg = 0; reg < 4; ++reg) {
            int irow = i_w + ti * 16 + quad * 4 + reg;
            int li   = labI[irow];
            int gi   = i0 + irow;
            float ps = 0.f, ns = 0.f;
            #pragma unroll
            for (int tj = 0; tj < 4; ++tj) {
                int jcol = j_w + tj * 16 + lrow;
                int lj   = labJ[jcol];
                int gj   = j0 + jcol;
                float w  = __expf(fmaf(acc[ti][tj][reg], 0.0625f, -1.0f));
                bool same = (li == lj);
                float wp = (same && (gi != gj)) ? w : 0.f;
                float wn = same ? 0.f : w;
                ps += wp;  ns += wn;
                psC[tj] += wp;  nsC[tj] += wn;
            }
            rowBuf[(size_t)(vR * 128 + irow) * 18 + lrow] = (float2){ps, ns};
        }
    }
    #pragma unroll
    for (int tj = 0; tj < 4; ++tj) {
        int jcol = j_w + tj * 16 + lrow;
        colBuf[(size_t)(vC * 128 + jcol) * 6 + quad] = (float2){psC[tj], nsC[tj]};
    }
    __syncthreads();

    if (tid < 128) {
        const float2* a = rowBuf + (size_t)tid * 18;
        const float2* b = rowBuf + (size_t)(128 + tid) * 18;
        float sp = 0.f, sn = 0.f;
        #pragma unroll
        for (int u = 0; u < 16; ++u) {
            sp += a[u].x + b[u].x;
            sn += a[u].y + b[u].y;
        }
        P[(size_t)bj * BN + i0 + tid] = sp;
        N[(size_t)bj * BN + i0 + tid] = sn;
    } else if (!diag) {
        int c = tid - 128;
        const float2* a = colBuf + (size_t)c * 6;
        const float2* b = colBuf + (size_t)(128 + c) * 6;
        float sp = 0.f, sn = 0.f;
        #pragma unroll
        for (int u = 0; u < 4; ++u) {
            sp += a[u].x + b[u].x;
            sn += a[u].y + b[u].y;
        }
        P[(size_t)bi * BN + j0 + c] = sp;
        N[(size_t)bi * BN + j0 + c] = sn;
    }
}

// Fused tail: 64 blocks x 128 threads. Per-block LDS histogram, per-row
// partial reduce + loss, one atomicAdd of the pre-scaled block sum into
// out[0] (zeroed by normalize_kernel).
__global__ __launch_bounds__(128) void reduce_finalize_kernel(
        const int* __restrict__ labels, const float* __restrict__ P,
        const float* __restrict__ N, float* __restrict__ out) {
    __shared__ int cnt[128];
    __shared__ float wsum[2];
    int tid = threadIdx.x;
    cnt[tid] = 0;
    __syncthreads();
    for (int i = tid; i < BN; i += 128) atomicAdd(&cnt[labels[i]], 1);
    __syncthreads();

    int i = blockIdx.x * 128 + tid;
    float p = 0.f, n = 0.f;
    #pragma unroll 8
    for (int c = 0; c < NB; ++c) {
        p += P[(size_t)c * BN + i];
        n += N[(size_t)c * BN + i];
    }
    int   c  = cnt[labels[i]];
    float pc = (float)(c - 1);
    float nc = (float)(BN - c);
    float pm = p / fmaxf(pc, 1.0f);
    float nm = n / fmaxf(nc, 1.0f);
    float v  = ((c - 1 > 0) && (BN - c > 0))
                   ? -logf(pm / (pm + nm + EPSF)) : 0.0f;
    v *= (1.0f / (float)BN);

    #pragma unroll
    for (int m = 1; m < 64; m <<= 1) v += __shfl_xor(v, m, 64);
    if ((tid & 63) == 0) wsum[tid >> 6] = v;
    __syncthreads();
    if (tid == 0) atomicAdd(out, wsum[0] + wsum[1]);
}

extern "C" void kernel_launch(void* const* d_in, const int* in_sizes, int n_in,
                              void* d_out, int out_size, void* d_ws, size_t ws_size,
                              hipStream_t stream) {
    const float* emb   = (const float*)d_in[0];
    const int* labels  = (const int*)d_in[1];
    float* out         = (float*)d_out;

    // ws layout: E (8 MB reserved; fp8 uses 4) | P (2 MB) | N (2 MB)
    unsigned char* E   = (unsigned char*)d_ws;
    float* P           = (float*)((char*)d_ws + (size_t)BN * DIM * 2);
    float* N           = P + (size_t)NB * BN;

    normalize_kernel<<<BN / 4, 256, 0, stream>>>(emb, E, out);
    gemm_epi_kernel<<<NB * (NB + 1) / 2, 256, 0, stream>>>(E, labels, P, N);
    reduce_finalize_kernel<<<NB, 128, 0, stream>>>(labels, P, N, out);
}